// Round 2
// baseline (274.937 us; speedup 1.0000x reference)
//
#include <hip/hip_runtime.h>
#include <math.h>

#define H_DIM 2880
#define E_NUM 32
#define TOPK 4
#define TT 32        // tokens per block
#define KW 96        // k-window per stage
#define NSTG 30      // H_DIM / KW
#define NBUF 3       // pipeline depth: compute s while s+1 (full) and s+2 (issuing) fly
#define GRP 776      // LDS group: 8 rows x 96 dw + 8 dw pad. 772->776: b128 tile-read
                     // start bank = (8tt+4ksl)%32 -> max 2-way (free) vs 4-way before
#define XB 0         // x buffers: XB + p*XBS, p=0..2
#define XBS 3104     // 4 groups x 776
#define WB 9312      // w buffers: WB + p*WBS  (= NBUF*XBS)
#define WBS 3104
#define SMSZ 18624   // 72.75 KiB -> 2 blocks/CU (145.5 KiB/CU)
#define REDR 36
#define LGTO 4608    // logits area (after red[4][32][36]); inside buffer-0 region only

// async global->LDS DMA, 16B/lane; dest = wave-uniform base + lane*16.
#define GLD16(gp, lp)                                                  \
    __builtin_amdgcn_global_load_lds(                                  \
        (const __attribute__((address_space(1))) void*)(gp),           \
        (__attribute__((address_space(3))) void*)(lp), 16, 0, 0)

// Grid 512 (2 blocks/CU), block 256 = 4 waves. Per lane: 8tok x 8exp tile,
// acc[64]; 16-way k-split: ks = wq*4 + ksl, lane = ksl*16 + et*4 + tt.
// Slice of KW=96: dw {ks*4+u,u<4} (b128) + {64+ks*2,+1} (b64).
//
// R8: replace per-stage __syncthreads (s_waitcnt vmcnt(0) drain -- kills the
// in-flight prefetch every 96-dw stage) with 3-buffer pipeline + counted
// vmcnt(6): wave waits only its own stage-s DMAs; stage s+1's 6 loads stay
// in flight ACROSS the barrier (T4 pattern). Buffer (s+2)%3 == (s-1)%3 is
// only written after the barrier, which proves all waves finished compute s-1.
__global__ __launch_bounds__(256, 2) void gate_fused(
    const float* __restrict__ x, const float* __restrict__ w,
    const float* __restrict__ bias, float* __restrict__ out, int T) {
    __shared__ float sm[SMSZ];
    const int tid = threadIdx.x;
    const int lane = tid & 63;
    const int wq = __builtin_amdgcn_readfirstlane(tid >> 6);
    const int tt = lane & 3;            // token group (8 tokens)
    const int et = (lane >> 2) & 3;     // expert group (8 experts)
    const int ksl = lane >> 4;          // intra-wave k-slice
    const int t0 = blockIdx.x * TT;

    // DMA: wave wq stages x-group wq (tokens 8wq..+8) and w-group wq (experts
    // 8wq..+8); 3 instrs each, 768 dw/group, lane-contiguous 16-B chunks.
    const float* gx[3]; const float* gw[3]; int lx[3], lw[3];
#pragma unroll
    for (int i = 0; i < 3; ++i) {
        const int d = i * 256 + lane * 4;   // dw within group
        const int r = d / KW, kk = d % KW;  // row, k-offset (no 16B straddle: 96%4==0)
        gx[i] = x + (size_t)(t0 + wq * 8 + r) * H_DIM + kk;
        gw[i] = w + (size_t)(wq * 8 + r) * H_DIM + kk;
        lx[i] = XB + wq * GRP + d;
        lw[i] = WB + wq * GRP + d;
    }

    float acc[64];
#pragma unroll
    for (int i = 0; i < 64; ++i) acc[i] = 0.f;

    // prologue: stage 0 -> buf0, stage 1 -> buf1 (12 DMAs in flight)
#pragma unroll
    for (int i = 0; i < 3; ++i) GLD16(gx[i], &sm[lx[i]]);
#pragma unroll
    for (int i = 0; i < 3; ++i) GLD16(gw[i], &sm[lw[i]]);
#pragma unroll
    for (int i = 0; i < 3; ++i) GLD16(gx[i] + KW, &sm[lx[i] + XBS]);
#pragma unroll
    for (int i = 0; i < 3; ++i) GLD16(gw[i] + KW, &sm[lw[i] + WBS]);

    const int ks = wq * 4 + ksl;
    const int koA = ks * 4;        // b128 unit, 16-B aligned
    const int koB = 64 + ks * 2;   // b64 unit, 8-B aligned

    int p = 0, pf = 2;             // compute buffer / prefetch buffer (uniform)
    for (int s = 0; s < NSTG; ++s) {
        // Wait OWN stage-s DMAs (oldest 6 of <=12 outstanding); do NOT drain
        // stage s+1's. Barrier then proves all waves' stage-s data resident
        // AND all waves are past compute s-1 (so buf pf is safe to overwrite).
        if (s + 1 < NSTG) {
            asm volatile("s_waitcnt vmcnt(6)" ::: "memory");
        } else {
            asm volatile("s_waitcnt vmcnt(0)" ::: "memory");
        }
        __builtin_amdgcn_s_barrier();
        asm volatile("" ::: "memory");  // fence: no ds_read hoists above barrier

        if (s + 2 < NSTG) {
            const size_t go = (size_t)(s + 2) * KW;
            const int xo = pf * XBS, wo = pf * WBS;
#pragma unroll
            for (int i = 0; i < 3; ++i) GLD16(gx[i] + go, &sm[lx[i] + xo]);
#pragma unroll
            for (int i = 0; i < 3; ++i) GLD16(gw[i] + go, &sm[lw[i] + wo]);
        }

        const float* xbp = &sm[XB + p * XBS + tt * GRP];
        const float* wbp = &sm[WB + p * WBS + et * GRP];

        float4 xa[8], wa[8];
#pragma unroll
        for (int i = 0; i < 8; ++i) xa[i] = *(const float4*)(xbp + i * KW + koA);
#pragma unroll
        for (int j = 0; j < 8; ++j) wa[j] = *(const float4*)(wbp + j * KW + koA);
#pragma unroll
        for (int i = 0; i < 8; ++i)
#pragma unroll
            for (int j = 0; j < 8; ++j)
                acc[i * 8 + j] += xa[i].x * wa[j].x + xa[i].y * wa[j].y +
                                  xa[i].z * wa[j].z + xa[i].w * wa[j].w;

        float2 x2[8], w2[8];
#pragma unroll
        for (int i = 0; i < 8; ++i) x2[i] = *(const float2*)(xbp + i * KW + koB);
#pragma unroll
        for (int j = 0; j < 8; ++j) w2[j] = *(const float2*)(wbp + j * KW + koB);
#pragma unroll
        for (int i = 0; i < 8; ++i)
#pragma unroll
            for (int j = 0; j < 8; ++j)
                acc[i * 8 + j] += x2[i].x * w2[j].x + x2[i].y * w2[j].y;

        p = (p == NBUF - 1) ? 0 : p + 1;
        pf = (pf == NBUF - 1) ? 0 : pf + 1;
    }

    __syncthreads();  // all compute + DMA done (vmcnt already 0); LDS repurposed

    // fold intra-wave k-slices: lanes l, l^16, l^32, l^48 share (tt,et)
#pragma unroll
    for (int d = 0; d < 64; ++d) {
        acc[d] += __shfl_xor(acc[d], 16, 64);
        acc[d] += __shfl_xor(acc[d], 32, 64);
    }

    // lanes 0-15 (ksl==0) park wave partial: red[wq][tok][e] (stride 36)
    if (ksl == 0) {
#pragma unroll
        for (int i = 0; i < 8; ++i) {
            float* rp = &sm[wq * (TT * REDR) + (tt * 8 + i) * REDR + et * 8];
            *(float4*)(rp + 0) = make_float4(acc[i * 8 + 0], acc[i * 8 + 1],
                                             acc[i * 8 + 2], acc[i * 8 + 3]);
            *(float4*)(rp + 4) = make_float4(acc[i * 8 + 4], acc[i * 8 + 5],
                                             acc[i * 8 + 6], acc[i * 8 + 7]);
        }
    }
    __syncthreads();

    // sum 4 wave partials + bias: thread -> 4 logits (tok = tid>>3, e4)
    {
        const int tok = tid >> 3, e4 = (tid & 7) * 4;
        float4 sg = *(const float4*)(bias + e4);
#pragma unroll
        for (int q = 0; q < 4; ++q) {
            float4 v = *(const float4*)&sm[q * (TT * REDR) + tok * REDR + e4];
            sg.x += v.x; sg.y += v.y; sg.z += v.z; sg.w += v.w;
        }
        *(float4*)&sm[LGTO + tok * REDR + e4] = sg;
    }
    __syncthreads();

    // first 32 lanes: per-token top-4 + softmax + store
    if (tid < TT) {
        const int t = t0 + tid;
        float logit[E_NUM];
#pragma unroll
        for (int j = 0; j < 8; ++j) {
            float4 v = *(const float4*)&sm[LGTO + tid * REDR + j * 4];
            logit[j * 4] = v.x; logit[j * 4 + 1] = v.y;
            logit[j * 4 + 2] = v.z; logit[j * 4 + 3] = v.w;
        }

        // top-4 descending, ties -> lowest index (strict >, ascending scan)
        int idx[TOPK];
        float val[TOPK];
#pragma unroll
        for (int k = 0; k < TOPK; ++k) {
            float best = -INFINITY;
            int bi = 0;
#pragma unroll
            for (int e = 0; e < E_NUM; ++e) {
                bool taken = false;
                for (int p2 = 0; p2 < k; ++p2) taken = taken || (idx[p2] == e);
                float v = logit[e];
                if (!taken && v > best) { best = v; bi = e; }
            }
            idx[k] = bi;
            val[k] = best;
        }
        float ex[TOPK], ssum = 0.f;
#pragma unroll
        for (int k = 0; k < TOPK; ++k) { ex[k] = expf(val[k] - val[0]); ssum += ex[k]; }
        const float inv = 1.f / ssum;

        *(float4*)(out + (size_t)t * 4) =
            make_float4((float)idx[0], (float)idx[1], (float)idx[2], (float)idx[3]);
        *(float4*)(out + (size_t)T * 4 + (size_t)t * 4) =
            make_float4(ex[0] * inv, ex[1] * inv, ex[2] * inv, ex[3] * inv);
    }
}

extern "C" void kernel_launch(void* const* d_in, const int* in_sizes, int n_in,
                              void* d_out, int out_size, void* d_ws, size_t ws_size,
                              hipStream_t stream) {
    const float* x    = (const float*)d_in[0];  // [B,S,H] fp32
    const float* w    = (const float*)d_in[1];  // [E,H] fp32
    const float* bias = (const float*)d_in[2];  // [E] fp32
    float* out = (float*)d_out;

    const int T = in_sizes[0] / H_DIM;  // 16384

    gate_fused<<<dim3(T / TT), 256, 0, stream>>>(x, w, bias, out, T);
}